// Round 2
// baseline (3555.046 us; speedup 1.0000x reference)
//
#include <hip/hip_runtime.h>
#include <math.h>

// Problem constants (S=2048, B=16, H=1024)
#define S_LEN 2048
#define B_SZ  16
#define H_SZ  1024
#define M_SZ  (S_LEN * B_SZ)   // 32768 rows of the fused GEMM

// ---------------------------------------------------------------------------
// K1: hp[b][h] = dot(hidden[b], W_att[h][0:1024]) + b_att[h]
// One wave per output element; coalesced reads of the W row.
// ---------------------------------------------------------------------------
__global__ void k_hidden_part(const float* __restrict__ hidden,
                              const float* __restrict__ W,
                              const float* __restrict__ b_att,
                              float* __restrict__ hp) {
    int gid  = blockIdx.x * blockDim.x + threadIdx.x;
    int wave = gid >> 6;
    int lane = threadIdx.x & 63;
    int b = wave >> 10;        // 1024 h per b
    int h = wave & 1023;
    const float* x = hidden + b * H_SZ;
    const float* w = W + (size_t)h * (2 * H_SZ);
    float acc = 0.f;
    #pragma unroll
    for (int k = 0; k < H_SZ; k += 64) acc += x[k + lane] * w[k + lane];
    #pragma unroll
    for (int off = 32; off; off >>= 1) acc += __shfl_down(acc, off, 64);
    if (lane == 0) hp[wave] = acc + b_att[h];
}

// ---------------------------------------------------------------------------
// K2: fused GEMM + tanh + dot-v.
//   score[m] = sum_h v[h] * tanh( hseq[m]·W2[h] + hp[m&15][h] )
// 128x128 tile, 256 threads, 8x8 accumulators/thread, double-buffered LDS.
// LDS = 2*(128*36)*2 matrices * 4B = 73728 B -> 2 workgroups/CU (8 waves/CU).
// The final cross-thread reduction buffer is OVERLAID on Xs (dead by then).
// ---------------------------------------------------------------------------
#define MT  128
#define NT  128
#define KT  32
#define LDK 36   // padded stride, 16B-aligned rows (36*4=144=9*16)

__global__ __launch_bounds__(256)
void k_score(const float* __restrict__ X,     // hseq, [32768][1024]
             const float* __restrict__ W,     // W_att, [1024][2048]; cols 1024..2047 = W2
             const float* __restrict__ hp,    // [16][1024]
             const float* __restrict__ v,     // [1024]
             float* __restrict__ score) {     // [32768]
    __shared__ float Xs[2][MT][LDK];
    __shared__ float Ws[2][NT][LDK];
    float (*red)[17] = (float (*)[17])&Xs[0][0][0];   // overlay: [128][17] = 8704 B < Xs

    const int tid = threadIdx.x;
    const int tx  = tid & 15;
    const int ty  = tid >> 4;
    const int m0  = blockIdx.x * MT;

    // staging: each thread loads 4 float4 per matrix per k-tile
    const int sr = tid >> 3;         // 0..31 (rows, 4 passes of 32)
    const int sk = (tid & 7) * 4;    // 0,4,...,28

    float part[8];
    #pragma unroll
    for (int i = 0; i < 8; ++i) part[i] = 0.f;

    for (int nt = 0; nt < 8; ++nt) {
        const int n0 = nt * NT;
        float acc[8][8];
        #pragma unroll
        for (int i = 0; i < 8; ++i)
            #pragma unroll
            for (int j = 0; j < 8; ++j) acc[i][j] = 0.f;

        // prologue: k-tile 0 -> LDS buf 0
        float4 xr[4], wr[4];
        #pragma unroll
        for (int p = 0; p < 4; ++p) {
            xr[p] = *(const float4*)(X + (size_t)(m0 + sr + 32*p) * 1024 + sk);
            wr[p] = *(const float4*)(W + (size_t)(n0 + sr + 32*p) * 2048 + 1024 + sk);
        }
        __syncthreads();   // protect Xs (red overlay) from previous nt's readers
        #pragma unroll
        for (int p = 0; p < 4; ++p) {
            *(float4*)&Xs[0][sr + 32*p][sk] = xr[p];
            *(float4*)&Ws[0][sr + 32*p][sk] = wr[p];
        }
        __syncthreads();

        for (int kt = 0; kt < 32; ++kt) {
            const int cur = kt & 1;
            if (kt < 31) {
                const int k0 = (kt + 1) * KT;
                #pragma unroll
                for (int p = 0; p < 4; ++p) {
                    xr[p] = *(const float4*)(X + (size_t)(m0 + sr + 32*p) * 1024 + k0 + sk);
                    wr[p] = *(const float4*)(W + (size_t)(n0 + sr + 32*p) * 2048 + 1024 + k0 + sk);
                }
            }
            // compute from LDS[cur]: rows ty+16i, cols tx+16j
            #pragma unroll
            for (int kk = 0; kk < KT; kk += 4) {
                float4 xv[8], wv[8];
                #pragma unroll
                for (int i = 0; i < 8; ++i)
                    xv[i] = *(const float4*)&Xs[cur][ty + 16*i][kk];
                #pragma unroll
                for (int j = 0; j < 8; ++j)
                    wv[j] = *(const float4*)&Ws[cur][tx + 16*j][kk];
                #pragma unroll
                for (int t = 0; t < 4; ++t)
                    #pragma unroll
                    for (int i = 0; i < 8; ++i)
                        #pragma unroll
                        for (int j = 0; j < 8; ++j)
                            acc[i][j] = fmaf(((const float*)&xv[i])[t],
                                             ((const float*)&wv[j])[t], acc[i][j]);
            }
            if (kt < 31) {
                #pragma unroll
                for (int p = 0; p < 4; ++p) {
                    *(float4*)&Xs[cur ^ 1][sr + 32*p][sk] = xr[p];
                    *(float4*)&Ws[cur ^ 1][sr + 32*p][sk] = wr[p];
                }
            }
            __syncthreads();
        }

        // epilogue: tanh + v-dot partials. b = m&15 = ty for all our rows.
        #pragma unroll
        for (int j = 0; j < 8; ++j) {
            const int c = n0 + tx + 16*j;
            const float hv = hp[ty * H_SZ + c];
            const float vv = v[c];
            #pragma unroll
            for (int i = 0; i < 8; ++i)
                part[i] += vv * tanhf(acc[i][j] + hv);
        }
    }

    // reduce partials over the 16 tx groups (red overlays Xs; all LDS reads
    // of Xs completed before the last kt barrier, epilogue touches no LDS)
    #pragma unroll
    for (int i = 0; i < 8; ++i) red[ty + 16*i][tx] = part[i];
    __syncthreads();
    if (tid < 128) {
        float s = 0.f;
        #pragma unroll
        for (int t = 0; t < 16; ++t) s += red[tid][t];
        score[m0 + tid] = s;
    }
}

// ---------------------------------------------------------------------------
// K3: mask + softmax over b (axis=1 of [S,B]) — 16 values per s, in-place.
// ---------------------------------------------------------------------------
__global__ void k_softmax(const float* __restrict__ score_in,
                          const int* __restrict__ masks,
                          float* __restrict__ wts) {
    int s = blockIdx.x * blockDim.x + threadIdx.x;
    if (s >= S_LEN) return;
    float vals[16];
    float mx = -INFINITY;
    #pragma unroll
    for (int b = 0; b < 16; ++b) {
        float sc = score_in[s * 16 + b];
        sc = masks[s * 16 + b] ? sc : -1e10f;
        vals[b] = sc;
        mx = fmaxf(mx, sc);
    }
    float sum = 0.f;
    #pragma unroll
    for (int b = 0; b < 16; ++b) { vals[b] = __expf(vals[b] - mx); sum += vals[b]; }
    float inv = 1.f / sum;
    #pragma unroll
    for (int b = 0; b < 16; ++b) wts[s * 16 + b] = vals[b] * inv;
}

// ---------------------------------------------------------------------------
// K4a: partial context sums over s-chunks (deterministic, no atomics)
//   partial[c][b][h] = sum_{s in chunk c} w[s,b] * hseq[s,b,h]
// ---------------------------------------------------------------------------
__global__ void k_context_partial(const float* __restrict__ wts,
                                  const float* __restrict__ X,
                                  float* __restrict__ partial) {
    int b = blockIdx.x & 15;
    int c = blockIdx.x >> 4;
    int h = threadIdx.x * 4;
    float4 acc = make_float4(0.f, 0.f, 0.f, 0.f);
    for (int s = c * 128; s < c * 128 + 128; ++s) {
        float w = wts[s * 16 + b];
        float4 x = *(const float4*)(X + (size_t)(s * 16 + b) * 1024 + h);
        acc.x += w * x.x; acc.y += w * x.y; acc.z += w * x.z; acc.w += w * x.w;
    }
    *(float4*)(partial + (size_t)(c * 16 + b) * 1024 + h) = acc;
}

// K4b: reduce the 16 chunks -> out[b*1024+h]  (shape [1,B,H] flat)
__global__ void k_context_reduce(const float* __restrict__ partial,
                                 float* __restrict__ out) {
    int o = blockIdx.x * blockDim.x + threadIdx.x;  // 16384
    int b = o >> 10, h = o & 1023;
    float s = 0.f;
    #pragma unroll
    for (int c = 0; c < 16; ++c) s += partial[(size_t)(c * 16 + b) * 1024 + h];
    out[o] = s;
}

extern "C" void kernel_launch(void* const* d_in, const int* in_sizes, int n_in,
                              void* d_out, int out_size, void* d_ws, size_t ws_size,
                              hipStream_t stream) {
    const float* hidden = (const float*)d_in[0];   // [1,16,1024]
    const float* hseq   = (const float*)d_in[1];   // [2048,16,1024]
    const int*   masks  = (const int*)d_in[2];     // [2048,16]
    const float* W      = (const float*)d_in[3];   // [1024,2048]
    const float* b_att  = (const float*)d_in[4];   // [1024]
    const float* v      = (const float*)d_in[5];   // [1024]
    float* out = (float*)d_out;                    // [1,16,1024] f32

    float* wsf     = (float*)d_ws;
    float* hp      = wsf;                          // 16384 f
    float* score   = wsf + 16384;                  // 32768 f (reused as weights)
    float* partial = wsf + 16384 + 32768;          // 262144 f

    hipLaunchKernelGGL(k_hidden_part,     dim3(4096), dim3(256), 0, stream, hidden, W, b_att, hp);
    hipLaunchKernelGGL(k_score,           dim3(M_SZ / MT), dim3(256), 0, stream, hseq, W, hp, v, score);
    hipLaunchKernelGGL(k_softmax,         dim3(8),    dim3(256), 0, stream, score, masks, score);
    hipLaunchKernelGGL(k_context_partial, dim3(256),  dim3(256), 0, stream, score, hseq, partial);
    hipLaunchKernelGGL(k_context_reduce,  dim3(64),   dim3(256), 0, stream, partial, out);
}

// Round 4
// 527.934 us; speedup vs baseline: 6.7339x; 6.7339x over previous
//
#include <hip/hip_runtime.h>
#include <math.h>

// Problem constants (S=2048, B=16, H=1024)
#define S_LEN 2048
#define B_SZ  16
#define H_SZ  1024
#define M_SZ  32768

typedef __attribute__((ext_vector_type(8))) short short8;   // bf16x8 (4 VGPR)
typedef __attribute__((ext_vector_type(4))) float f32x4;    // MFMA C/D

// ---------------------------------------------------------------------------
// bf16 split helpers: x ~= hi + lo, both RNE-rounded bf16
// ---------------------------------------------------------------------------
__device__ __forceinline__ unsigned bf16_rne(float x) {
    unsigned u = __float_as_uint(x);
    u += 0x7fff + ((u >> 16) & 1);
    return u >> 16;
}
__device__ __forceinline__ void split4(float4 f, uint2& hi, uint2& lo) {
    unsigned h0 = bf16_rne(f.x), h1 = bf16_rne(f.y), h2 = bf16_rne(f.z), h3 = bf16_rne(f.w);
    float r0 = f.x - __uint_as_float(h0 << 16);
    float r1 = f.y - __uint_as_float(h1 << 16);
    float r2 = f.z - __uint_as_float(h2 << 16);
    float r3 = f.w - __uint_as_float(h3 << 16);
    hi.x = h0 | (h1 << 16);  hi.y = h2 | (h3 << 16);
    lo.x = bf16_rne(r0) | (bf16_rne(r1) << 16);
    lo.y = bf16_rne(r2) | (bf16_rne(r3) << 16);
}

// ---------------------------------------------------------------------------
// K1: hp[b][h] = dot(hidden[b], W_att[h][0:1024]) + b_att[h]   (fp32, exact)
// ---------------------------------------------------------------------------
__global__ void k_hidden_part(const float* __restrict__ hidden,
                              const float* __restrict__ W,
                              const float* __restrict__ b_att,
                              float* __restrict__ hp) {
    int gid  = blockIdx.x * blockDim.x + threadIdx.x;
    int wave = gid >> 6;
    int lane = threadIdx.x & 63;
    int b = wave >> 10;
    int h = wave & 1023;
    const float* x = hidden + b * H_SZ;
    const float* w = W + (size_t)h * (2 * H_SZ);
    float acc = 0.f;
    #pragma unroll
    for (int k = 0; k < H_SZ; k += 64) acc += x[k + lane] * w[k + lane];
    #pragma unroll
    for (int off = 32; off; off >>= 1) acc += __shfl_down(acc, off, 64);
    if (lane == 0) hp[wave] = acc + b_att[h];
}

// ---------------------------------------------------------------------------
// K2: fused split-bf16 MFMA GEMM + tanh + v-dot.
//   pre[m,c] = sum_k X[m,k]*W[c][1024+k]  via 3 MFMA products (hh, hl, lh)
//   score_part[nt][m] = sum_{c in n-tile} v[c]*tanh(pre + hp[m&15][c])
// Tile 128(M) x 256(N), BK=32, 512 thr = 8 waves (2x4), per-wave 64x64.
// Cross-wave (wn) column reduction goes through a 2 KB LDS array overlaid
// on the (dead) staging buffers after the K loop.
// ---------------------------------------------------------------------------
#define LROWB 80                       // bytes per LDS row (40 bf16)
#define A_HI  0
#define A_LO  (128 * LROWB)            // 10240
#define B_HI  (A_LO + 128 * LROWB)     // 20480
#define B_LO  (B_HI + 256 * LROWB)     // 40960
#define BUFSZ (B_LO + 256 * LROWB)     // 61440

__global__ __launch_bounds__(512, 2)
void k_score_mfma(const float* __restrict__ X,      // [32768][1024]
                  const float* __restrict__ W,      // [1024][2048]
                  const float* __restrict__ hp,     // [16][1024]
                  const float* __restrict__ v,      // [1024]
                  float* __restrict__ score_part) { // [4][32768]
    __shared__ char lds[2 * BUFSZ];    // 120 KB

    const int t = threadIdx.x;
    // XCD-chunked bijective swizzle (1024 wgs, 1024%8==0): each XCD gets a
    // contiguous run of m-major ids so the 4 n-blocks of an X panel share L2.
    int wg = (blockIdx.x & 7) * 128 + (blockIdx.x >> 3);
    const int m0 = (wg >> 2) * 128;
    const int nt = wg & 3;
    const int n0 = nt * 256;

    const int lane = t & 63, wid = t >> 6;
    const int wm = wid >> 2, wn = wid & 3;      // 2 x 4 waves
    const int lr = lane & 15, lq = lane >> 4;

    // staging: thread t covers row srow(+64p), k = skq*4 .. +3
    const int srow = t >> 3;
    const int skq  = t & 7;

    const float* Xp = X + (size_t)(m0 + srow) * 1024 + skq * 4;
    const float* Wp = W + (size_t)(n0 + srow) * 2048 + 1024 + skq * 4;

    f32x4 acc[4][4];
    #pragma unroll
    for (int i = 0; i < 4; ++i)
        #pragma unroll
        for (int j = 0; j < 4; ++j) acc[i][j] = (f32x4)0.f;

    float4 ax[2], bx[4];

#define LOADG(kt)                                                              \
    {                                                                          \
        const int ko = (kt) * 32;                                              \
        ax[0] = *(const float4*)(Xp + ko);                                     \
        ax[1] = *(const float4*)(Xp + 64 * 1024 + ko);                         \
        bx[0] = *(const float4*)(Wp + ko);                                     \
        bx[1] = *(const float4*)(Wp + 64 * 2048 + ko);                         \
        bx[2] = *(const float4*)(Wp + 128 * 2048 + ko);                        \
        bx[3] = *(const float4*)(Wp + 192 * 2048 + ko);                        \
    }

#define STAGE(buf)                                                             \
    {                                                                          \
        uint2 h, l;                                                            \
        _Pragma("unroll")                                                      \
        for (int p = 0; p < 2; ++p) {                                          \
            split4(ax[p], h, l);                                               \
            int ro = (srow + 64 * p) * LROWB + skq * 8;                        \
            *(uint2*)((buf) + A_HI + ro) = h;                                  \
            *(uint2*)((buf) + A_LO + ro) = l;                                  \
        }                                                                      \
        _Pragma("unroll")                                                      \
        for (int p = 0; p < 4; ++p) {                                          \
            split4(bx[p], h, l);                                               \
            int ro = (srow + 64 * p) * LROWB + skq * 8;                        \
            *(uint2*)((buf) + B_HI + ro) = h;                                  \
            *(uint2*)((buf) + B_LO + ro) = l;                                  \
        }                                                                      \
    }

    LOADG(0);
    STAGE(lds);
    __syncthreads();

    for (int kt = 0; kt < 32; ++kt) {
        char* cur = lds + (kt & 1) * BUFSZ;
        char* nxt = lds + ((kt & 1) ^ 1) * BUFSZ;
        if (kt < 31) LOADG(kt + 1);

        // fragment reads: lane holds [row=lr][k = lq*8 .. +7] (16 B)
        short8 ah[4], al[4], bh[4], bl[4];
        #pragma unroll
        for (int i = 0; i < 4; ++i) {
            int ro = (wm * 64 + i * 16 + lr) * LROWB + lq * 16;
            ah[i] = *(const short8*)(cur + A_HI + ro);
            al[i] = *(const short8*)(cur + A_LO + ro);
        }
        #pragma unroll
        for (int j = 0; j < 4; ++j) {
            int ro = (wn * 64 + j * 16 + lr) * LROWB + lq * 16;
            bh[j] = *(const short8*)(cur + B_HI + ro);
            bl[j] = *(const short8*)(cur + B_LO + ro);
        }
        // 3 products, acc reuse distance 16 (no dependency stalls)
        #pragma unroll
        for (int i = 0; i < 4; ++i)
            #pragma unroll
            for (int j = 0; j < 4; ++j)
                acc[i][j] = __builtin_amdgcn_mfma_f32_16x16x32_bf16(ah[i], bh[j], acc[i][j], 0, 0, 0);
        #pragma unroll
        for (int i = 0; i < 4; ++i)
            #pragma unroll
            for (int j = 0; j < 4; ++j)
                acc[i][j] = __builtin_amdgcn_mfma_f32_16x16x32_bf16(ah[i], bl[j], acc[i][j], 0, 0, 0);
        #pragma unroll
        for (int i = 0; i < 4; ++i)
            #pragma unroll
            for (int j = 0; j < 4; ++j)
                acc[i][j] = __builtin_amdgcn_mfma_f32_16x16x32_bf16(al[i], bh[j], acc[i][j], 0, 0, 0);

        if (kt < 31) STAGE(nxt);
        __syncthreads();
    }

    // --- epilogue ---------------------------------------------------------
    // D element at lane(lq,lr), reg r of subtile (i,j):
    //   row = wm*64 + i*16 + lq*4 + r   (global row & 15 == lq*4+r == b)
    //   col = wn*64 + j*16 + lr
    // Per-wave partial sum over its 64 cols -> LDS red[wn][128] -> sum wn.
    float* red = (float*)lds;          // [4][128] floats, staging is dead
    #pragma unroll
    for (int i = 0; i < 4; ++i) {
        #pragma unroll
        for (int r = 0; r < 4; ++r) {
            const int b = lq * 4 + r;
            float s = 0.f;
            #pragma unroll
            for (int j = 0; j < 4; ++j) {
                const int c = n0 + wn * 64 + j * 16 + lr;
                s += v[c] * tanhf(acc[i][j][r] + hp[b * H_SZ + c]);
            }
            s += __shfl_xor(s, 1);
            s += __shfl_xor(s, 2);
            s += __shfl_xor(s, 4);
            s += __shfl_xor(s, 8);
            if (lr == 0)
                red[wn * 128 + wm * 64 + i * 16 + lq * 4 + r] = s;
        }
    }
    __syncthreads();
    if (t < 128) {
        float sc = red[t] + red[128 + t] + red[256 + t] + red[384 + t];
        score_part[nt * M_SZ + m0 + t] = sc;
    }
#undef LOADG
#undef STAGE
}

// ---------------------------------------------------------------------------
// K3: fold 4 n-tile partials, mask, softmax over b (16 values per s)
// ---------------------------------------------------------------------------
__global__ void k_softmax(const float* __restrict__ part,
                          const int* __restrict__ masks,
                          float* __restrict__ wts) {
    int s = blockIdx.x * blockDim.x + threadIdx.x;
    if (s >= S_LEN) return;
    float vals[16];
    float mx = -INFINITY;
    #pragma unroll
    for (int b = 0; b < 16; ++b) {
        int m = s * 16 + b;
        float sc = part[m] + part[M_SZ + m] + part[2 * M_SZ + m] + part[3 * M_SZ + m];
        sc = masks[m] ? sc : -1e10f;
        vals[b] = sc;
        mx = fmaxf(mx, sc);
    }
    float sum = 0.f;
    #pragma unroll
    for (int b = 0; b < 16; ++b) { vals[b] = __expf(vals[b] - mx); sum += vals[b]; }
    float inv = 1.f / sum;
    #pragma unroll
    for (int b = 0; b < 16; ++b) wts[s * 16 + b] = vals[b] * inv;
}

// ---------------------------------------------------------------------------
// K4a/K4b: context = sum_s w[s,b]*X[s,b,:]  (deterministic two-stage)
// ---------------------------------------------------------------------------
__global__ void k_context_partial(const float* __restrict__ wts,
                                  const float* __restrict__ X,
                                  float* __restrict__ partial) {
    int b = blockIdx.x & 15;
    int c = blockIdx.x >> 4;
    int h = threadIdx.x * 4;
    float4 acc = make_float4(0.f, 0.f, 0.f, 0.f);
    for (int s = c * 128; s < c * 128 + 128; ++s) {
        float w = wts[s * 16 + b];
        float4 x = *(const float4*)(X + (size_t)(s * 16 + b) * 1024 + h);
        acc.x += w * x.x; acc.y += w * x.y; acc.z += w * x.z; acc.w += w * x.w;
    }
    *(float4*)(partial + (size_t)(c * 16 + b) * 1024 + h) = acc;
}

__global__ void k_context_reduce(const float* __restrict__ partial,
                                 float* __restrict__ out) {
    int o = blockIdx.x * blockDim.x + threadIdx.x;  // 16384
    int b = o >> 10, h = o & 1023;
    float s = 0.f;
    #pragma unroll
    for (int c = 0; c < 16; ++c) s += partial[(size_t)(c * 16 + b) * 1024 + h];
    out[o] = s;
}

extern "C" void kernel_launch(void* const* d_in, const int* in_sizes, int n_in,
                              void* d_out, int out_size, void* d_ws, size_t ws_size,
                              hipStream_t stream) {
    const float* hidden = (const float*)d_in[0];
    const float* hseq   = (const float*)d_in[1];
    const int*   masks  = (const int*)d_in[2];
    const float* b_att  = (const float*)d_in[4];
    const float* W      = (const float*)d_in[3];
    const float* v      = (const float*)d_in[5];
    float* out = (float*)d_out;

    // ws layout (floats): hp[16384] | score[32768] | scratch[262144]
    // scratch = score_part[4*32768] for K2/K3, then partial[16*16384] for K4.
    // Total 311,296 floats = 1.19 MB (same footprint as the passing R2 run).
    float* wsf        = (float*)d_ws;
    float* hp         = wsf;
    float* score      = wsf + 16384;
    float* scratch    = wsf + 16384 + 32768;

    hipLaunchKernelGGL(k_hidden_part,     dim3(4096), dim3(256), 0, stream, hidden, W, b_att, hp);
    hipLaunchKernelGGL(k_score_mfma,      dim3(1024), dim3(512), 0, stream, hseq, W, hp, v, scratch);
    hipLaunchKernelGGL(k_softmax,         dim3(8),    dim3(256), 0, stream, scratch, masks, score);
    hipLaunchKernelGGL(k_context_partial, dim3(256),  dim3(256), 0, stream, score, hseq, scratch);
    hipLaunchKernelGGL(k_context_reduce,  dim3(64),   dim3(256), 0, stream, scratch, out);
}

// Round 5
// 500.331 us; speedup vs baseline: 7.1054x; 1.0552x over previous
//
#include <hip/hip_runtime.h>
#include <math.h>

// Problem constants (S=2048, B=16, H=1024)
#define S_LEN 2048
#define B_SZ  16
#define H_SZ  1024
#define M_SZ  32768

typedef __attribute__((ext_vector_type(8))) short short8;   // bf16x8 (4 VGPR)
typedef __attribute__((ext_vector_type(4))) float f32x4;    // MFMA C/D

// ---------------------------------------------------------------------------
// bf16 split helpers: x ~= hi + lo, both RNE-rounded bf16
// ---------------------------------------------------------------------------
__device__ __forceinline__ unsigned bf16_rne(float x) {
    unsigned u = __float_as_uint(x);
    u += 0x7fff + ((u >> 16) & 1);
    return u >> 16;
}
__device__ __forceinline__ void split4(float4 f, uint2& hi, uint2& lo) {
    unsigned h0 = bf16_rne(f.x), h1 = bf16_rne(f.y), h2 = bf16_rne(f.z), h3 = bf16_rne(f.w);
    float r0 = f.x - __uint_as_float(h0 << 16);
    float r1 = f.y - __uint_as_float(h1 << 16);
    float r2 = f.z - __uint_as_float(h2 << 16);
    float r3 = f.w - __uint_as_float(h3 << 16);
    hi.x = h0 | (h1 << 16);  hi.y = h2 | (h3 << 16);
    lo.x = bf16_rne(r0) | (bf16_rne(r1) << 16);
    lo.y = bf16_rne(r2) | (bf16_rne(r3) << 16);
}

// ---------------------------------------------------------------------------
// K0 (fast path): pre-split W2 = W[:,1024:2048] into bf16 hi/lo [1024][1024]
// ---------------------------------------------------------------------------
__global__ void k_split_w(const float* __restrict__ W,
                          unsigned short* __restrict__ Wh,
                          unsigned short* __restrict__ Wl) {
    int idx = blockIdx.x * blockDim.x + threadIdx.x;   // 262144 float4 units
    int h = idx >> 8, c4 = idx & 255;
    float4 f = *(const float4*)(W + (size_t)h * 2048 + 1024 + c4 * 4);
    uint2 hi, lo;
    split4(f, hi, lo);
    *(uint2*)(Wh + (size_t)h * 1024 + c4 * 4) = hi;
    *(uint2*)(Wl + (size_t)h * 1024 + c4 * 4) = lo;
}

// ---------------------------------------------------------------------------
// K1: hp[b][h] = dot(hidden[b], W_att[h][0:1024]) + b_att[h]   (fp32, exact)
// One wave per h computes ALL 16 b (W row read once: 4 MB total, not 64 MB).
// hidden (64 KB) staged in LDS.
// ---------------------------------------------------------------------------
__global__ __launch_bounds__(256)
void k_hidden_part2(const float* __restrict__ hidden,
                    const float* __restrict__ W,
                    const float* __restrict__ b_att,
                    float* __restrict__ hp) {
    __shared__ float hid[B_SZ * H_SZ];                 // 64 KB
    const int t = threadIdx.x;
    #pragma unroll
    for (int i = 0; i < 16; ++i)
        *(float4*)&hid[(t + i * 256) * 4] = *(const float4*)(hidden + (t + i * 256) * 4);
    __syncthreads();

    const int lane = t & 63;
    const int h = blockIdx.x * 4 + (t >> 6);
    const float* w = W + (size_t)h * 2048;
    float acc[16];
    #pragma unroll
    for (int b = 0; b < 16; ++b) acc[b] = 0.f;
    for (int k = 0; k < H_SZ; k += 64) {
        float wv = w[k + lane];
        #pragma unroll
        for (int b = 0; b < 16; ++b) acc[b] = fmaf(wv, hid[b * H_SZ + k + lane], acc[b]);
    }
    #pragma unroll
    for (int b = 0; b < 16; ++b) {
        float s = acc[b];
        s += __shfl_xor(s, 1);  s += __shfl_xor(s, 2);  s += __shfl_xor(s, 4);
        s += __shfl_xor(s, 8);  s += __shfl_xor(s, 16); s += __shfl_xor(s, 32);
        if (lane == 0) hp[b * H_SZ + h] = s + b_att[h];
    }
}

// ===========================================================================
// K2 FAST: split-bf16 MFMA GEMM + tanh + v-dot, pre-split B, XOR-swizzled LDS
// Tile 128(M) x 256(N), BK=32, 512 thr = 8 waves (2x4), per-wave 64x64.
// LDS rows 64 B (32 bf16), swizzle: phys_slot16B = slot ^ ((row>>2)&3),
// applied on BOTH ds_write and ds_read (reg-staged).  96 KB double-buffered.
// ===========================================================================
#define FA_HI 0
#define FA_LO 8192
#define FB_HI 16384
#define FB_LO 32768
#define FBUF  49152

__global__ __launch_bounds__(512, 2)
void k_score_fast(const float* __restrict__ X,            // [32768][1024] f32
                  const unsigned short* __restrict__ Wh,  // [1024][1024] bf16
                  const unsigned short* __restrict__ Wl,
                  const float* __restrict__ hp,           // [16][1024]
                  const float* __restrict__ v,            // [1024]
                  float* __restrict__ score_part) {       // [4][32768]
    __shared__ char lds[2 * FBUF];

    const int t = threadIdx.x;
    int wg = (blockIdx.x & 7) * 128 + (blockIdx.x >> 3);  // XCD-chunked swizzle
    const int m0 = (wg >> 2) * 128;
    const int nt = wg & 3;
    const int n0 = nt * 256;

    const int lane = t & 63, wid = t >> 6;
    const int wm = wid >> 2, wn = wid & 3;
    const int lr = lane & 15, lq = lane >> 4;
    const int sw = (lq ^ (lr >> 2)) << 4;                 // read-side swizzle

    // A staging: thread covers rows srowA, srowA+64 at k = skqA*4..+3 (f32)
    const int srowA = t >> 3, skqA = t & 7;
    // B staging: thread covers rows rB, rB+128 at slot = slotB (16 B = 8 bf16)
    const int rB = t >> 2, slotB = t & 3;

    const float* Xp = X + (size_t)(m0 + srowA) * 1024 + skqA * 4;
    const unsigned short* Whp = Wh + (size_t)(n0 + rB) * 1024 + slotB * 8;
    const unsigned short* Wlp = Wl + (size_t)(n0 + rB) * 1024 + slotB * 8;

    // write-side swizzled offsets (row>>2 masks are p-invariant)
    const int aSw = ((skqA >> 1) ^ ((srowA >> 2) & 3)) << 4;
    const int aOff = srowA * 64 + aSw + (skqA & 1) * 8;
    const int bSw = (slotB ^ ((rB >> 2) & 3)) << 4;
    const int bOff = rB * 64 + bSw;

    f32x4 acc[4][4];
    #pragma unroll
    for (int i = 0; i < 4; ++i)
        #pragma unroll
        for (int j = 0; j < 4; ++j) acc[i][j] = (f32x4)0.f;

    float4 ax[2];
    short8 sbh[2], sbl[2];

#define LOADG_F(kt)                                                            \
    {                                                                          \
        const int ko = (kt) * 32;                                              \
        ax[0]  = *(const float4*)(Xp + ko);                                    \
        ax[1]  = *(const float4*)(Xp + 64 * 1024 + ko);                        \
        sbh[0] = *(const short8*)(Whp + ko);                                   \
        sbh[1] = *(const short8*)(Whp + 128 * 1024 + ko);                      \
        sbl[0] = *(const short8*)(Wlp + ko);                                   \
        sbl[1] = *(const short8*)(Wlp + 128 * 1024 + ko);                      \
    }

#define STAGE_F(buf)                                                           \
    {                                                                          \
        uint2 h, l;                                                            \
        _Pragma("unroll")                                                      \
        for (int p = 0; p < 2; ++p) {                                          \
            split4(ax[p], h, l);                                               \
            *(uint2*)((buf) + FA_HI + aOff + p * 64 * 64) = h;                 \
            *(uint2*)((buf) + FA_LO + aOff + p * 64 * 64) = l;                 \
        }                                                                      \
        _Pragma("unroll")                                                      \
        for (int p = 0; p < 2; ++p) {                                          \
            *(short8*)((buf) + FB_HI + bOff + p * 128 * 64) = sbh[p];          \
            *(short8*)((buf) + FB_LO + bOff + p * 128 * 64) = sbl[p];          \
        }                                                                      \
    }

    LOADG_F(0);
    STAGE_F(lds);
    __syncthreads();

    for (int kt = 0; kt < 32; ++kt) {
        char* cur = lds + (kt & 1) * FBUF;
        char* nxt = lds + ((kt & 1) ^ 1) * FBUF;
        if (kt < 31) LOADG_F(kt + 1);

        short8 ah[4], al[4], bh[4], bl[4];
        #pragma unroll
        for (int i = 0; i < 4; ++i) {
            int ro = (wm * 64 + i * 16 + lr) * 64 + sw;
            ah[i] = *(const short8*)(cur + FA_HI + ro);
            al[i] = *(const short8*)(cur + FA_LO + ro);
        }
        #pragma unroll
        for (int j = 0; j < 4; ++j) {
            int ro = (wn * 64 + j * 16 + lr) * 64 + sw;
            bh[j] = *(const short8*)(cur + FB_HI + ro);
            bl[j] = *(const short8*)(cur + FB_LO + ro);
        }
        #pragma unroll
        for (int i = 0; i < 4; ++i)
            #pragma unroll
            for (int j = 0; j < 4; ++j)
                acc[i][j] = __builtin_amdgcn_mfma_f32_16x16x32_bf16(ah[i], bh[j], acc[i][j], 0, 0, 0);
        #pragma unroll
        for (int i = 0; i < 4; ++i)
            #pragma unroll
            for (int j = 0; j < 4; ++j)
                acc[i][j] = __builtin_amdgcn_mfma_f32_16x16x32_bf16(ah[i], bl[j], acc[i][j], 0, 0, 0);
        #pragma unroll
        for (int i = 0; i < 4; ++i)
            #pragma unroll
            for (int j = 0; j < 4; ++j)
                acc[i][j] = __builtin_amdgcn_mfma_f32_16x16x32_bf16(al[i], bh[j], acc[i][j], 0, 0, 0);

        if (kt < 31) STAGE_F(nxt);
        __syncthreads();
    }

    // epilogue: D[row = wm*64+i*16+lq*4+r][col = wn*64+j*16+lr]
    float* red = (float*)lds;          // [4][128], staging dead
    #pragma unroll
    for (int i = 0; i < 4; ++i) {
        #pragma unroll
        for (int r = 0; r < 4; ++r) {
            const int b = lq * 4 + r;
            float s = 0.f;
            #pragma unroll
            for (int j = 0; j < 4; ++j) {
                const int c = n0 + wn * 64 + j * 16 + lr;
                s += v[c] * tanhf(acc[i][j][r] + hp[b * H_SZ + c]);
            }
            s += __shfl_xor(s, 1);
            s += __shfl_xor(s, 2);
            s += __shfl_xor(s, 4);
            s += __shfl_xor(s, 8);
            if (lr == 0)
                red[wn * 128 + wm * 64 + i * 16 + lq * 4 + r] = s;
        }
    }
    __syncthreads();
    if (t < 128)
        score_part[nt * M_SZ + m0 + t] = red[t] + red[128 + t] + red[256 + t] + red[384 + t];
#undef LOADG_F
#undef STAGE_F
}

// ===========================================================================
// K2 FALLBACK (proven R4 kernel): in-kernel split of both A and B
// ===========================================================================
#define LROWB 80
#define A_HI  0
#define A_LO  (128 * LROWB)
#define B_HI  (A_LO + 128 * LROWB)
#define B_LO  (B_HI + 256 * LROWB)
#define BUFSZ (B_LO + 256 * LROWB)

__global__ __launch_bounds__(512, 2)
void k_score_mfma(const float* __restrict__ X,
                  const float* __restrict__ W,
                  const float* __restrict__ hp,
                  const float* __restrict__ v,
                  float* __restrict__ score_part) {
    __shared__ char lds[2 * BUFSZ];

    const int t = threadIdx.x;
    int wg = (blockIdx.x & 7) * 128 + (blockIdx.x >> 3);
    const int m0 = (wg >> 2) * 128;
    const int nt = wg & 3;
    const int n0 = nt * 256;

    const int lane = t & 63, wid = t >> 6;
    const int wm = wid >> 2, wn = wid & 3;
    const int lr = lane & 15, lq = lane >> 4;
    const int srow = t >> 3;
    const int skq  = t & 7;

    const float* Xp = X + (size_t)(m0 + srow) * 1024 + skq * 4;
    const float* Wp = W + (size_t)(n0 + srow) * 2048 + 1024 + skq * 4;

    f32x4 acc[4][4];
    #pragma unroll
    for (int i = 0; i < 4; ++i)
        #pragma unroll
        for (int j = 0; j < 4; ++j) acc[i][j] = (f32x4)0.f;

    float4 ax[2], bx[4];

#define LOADG(kt)                                                              \
    {                                                                          \
        const int ko = (kt) * 32;                                              \
        ax[0] = *(const float4*)(Xp + ko);                                     \
        ax[1] = *(const float4*)(Xp + 64 * 1024 + ko);                         \
        bx[0] = *(const float4*)(Wp + ko);                                     \
        bx[1] = *(const float4*)(Wp + 64 * 2048 + ko);                         \
        bx[2] = *(const float4*)(Wp + 128 * 2048 + ko);                        \
        bx[3] = *(const float4*)(Wp + 192 * 2048 + ko);                        \
    }

#define STAGE(buf)                                                             \
    {                                                                          \
        uint2 h, l;                                                            \
        _Pragma("unroll")                                                      \
        for (int p = 0; p < 2; ++p) {                                          \
            split4(ax[p], h, l);                                               \
            int ro = (srow + 64 * p) * LROWB + skq * 8;                        \
            *(uint2*)((buf) + A_HI + ro) = h;                                  \
            *(uint2*)((buf) + A_LO + ro) = l;                                  \
        }                                                                      \
        _Pragma("unroll")                                                      \
        for (int p = 0; p < 4; ++p) {                                          \
            split4(bx[p], h, l);                                               \
            int ro = (srow + 64 * p) * LROWB + skq * 8;                        \
            *(uint2*)((buf) + B_HI + ro) = h;                                  \
            *(uint2*)((buf) + B_LO + ro) = l;                                  \
        }                                                                      \
    }

    LOADG(0);
    STAGE(lds);
    __syncthreads();

    for (int kt = 0; kt < 32; ++kt) {
        char* cur = lds + (kt & 1) * BUFSZ;
        char* nxt = lds + ((kt & 1) ^ 1) * BUFSZ;
        if (kt < 31) LOADG(kt + 1);

        short8 ah[4], al[4], bh[4], bl[4];
        #pragma unroll
        for (int i = 0; i < 4; ++i) {
            int ro = (wm * 64 + i * 16 + lr) * LROWB + lq * 16;
            ah[i] = *(const short8*)(cur + A_HI + ro);
            al[i] = *(const short8*)(cur + A_LO + ro);
        }
        #pragma unroll
        for (int j = 0; j < 4; ++j) {
            int ro = (wn * 64 + j * 16 + lr) * LROWB + lq * 16;
            bh[j] = *(const short8*)(cur + B_HI + ro);
            bl[j] = *(const short8*)(cur + B_LO + ro);
        }
        #pragma unroll
        for (int i = 0; i < 4; ++i)
            #pragma unroll
            for (int j = 0; j < 4; ++j)
                acc[i][j] = __builtin_amdgcn_mfma_f32_16x16x32_bf16(ah[i], bh[j], acc[i][j], 0, 0, 0);
        #pragma unroll
        for (int i = 0; i < 4; ++i)
            #pragma unroll
            for (int j = 0; j < 4; ++j)
                acc[i][j] = __builtin_amdgcn_mfma_f32_16x16x32_bf16(ah[i], bl[j], acc[i][j], 0, 0, 0);
        #pragma unroll
        for (int i = 0; i < 4; ++i)
            #pragma unroll
            for (int j = 0; j < 4; ++j)
                acc[i][j] = __builtin_amdgcn_mfma_f32_16x16x32_bf16(al[i], bh[j], acc[i][j], 0, 0, 0);

        if (kt < 31) STAGE(nxt);
        __syncthreads();
    }

    float* red = (float*)lds;
    #pragma unroll
    for (int i = 0; i < 4; ++i) {
        #pragma unroll
        for (int r = 0; r < 4; ++r) {
            const int b = lq * 4 + r;
            float s = 0.f;
            #pragma unroll
            for (int j = 0; j < 4; ++j) {
                const int c = n0 + wn * 64 + j * 16 + lr;
                s += v[c] * tanhf(acc[i][j][r] + hp[b * H_SZ + c]);
            }
            s += __shfl_xor(s, 1);
            s += __shfl_xor(s, 2);
            s += __shfl_xor(s, 4);
            s += __shfl_xor(s, 8);
            if (lr == 0)
                red[wn * 128 + wm * 64 + i * 16 + lq * 4 + r] = s;
        }
    }
    __syncthreads();
    if (t < 128)
        score_part[nt * M_SZ + m0 + t] = red[t] + red[128 + t] + red[256 + t] + red[384 + t];
#undef LOADG
#undef STAGE
}

// ---------------------------------------------------------------------------
// K3: fused softmax + context partial.  Block (c,b): 128 s-steps for batch b.
// Phase 1: threads 0..127 compute softmax weight w[s,b] into LDS.
// Phase 2: 2 thread-halves each accumulate 64 s-steps over 1024 h, LDS-reduce.
// ---------------------------------------------------------------------------
__global__ __launch_bounds__(512)
void k_context_sm(const float* __restrict__ part,    // [4][32768] scores
                  const int* __restrict__ masks,
                  const float* __restrict__ X,
                  float* __restrict__ partial) {     // [16][16][1024]
    __shared__ float wlds[128];
    __shared__ float4 red4[256];

    const int t = threadIdx.x;
    const int b = blockIdx.x & 15;
    const int c = blockIdx.x >> 4;

    if (t < 128) {
        const int s = c * 128 + t;
        float vals[16];
        float mx = -INFINITY;
        #pragma unroll
        for (int bb = 0; bb < 16; ++bb) {
            int m = s * 16 + bb;
            float sc = part[m] + part[M_SZ + m] + part[2 * M_SZ + m] + part[3 * M_SZ + m];
            sc = masks[m] ? sc : -1e10f;
            vals[bb] = sc;
            mx = fmaxf(mx, sc);
        }
        float sum = 0.f;
        #pragma unroll
        for (int bb = 0; bb < 16; ++bb) { vals[bb] = __expf(vals[bb] - mx); sum += vals[bb]; }
        wlds[t] = vals[b] / sum;
    }
    __syncthreads();

    const int half = t >> 8, tt = t & 255;
    const int h = tt * 4;
    float4 acc = make_float4(0.f, 0.f, 0.f, 0.f);
    #pragma unroll 4
    for (int i = 0; i < 64; ++i) {
        const int sl = half * 64 + i;
        float w = wlds[sl];
        float4 x = *(const float4*)(X + ((size_t)((c * 128 + sl) * 16 + b)) * 1024 + h);
        acc.x += w * x.x; acc.y += w * x.y; acc.z += w * x.z; acc.w += w * x.w;
    }
    if (half == 1) red4[tt] = acc;
    __syncthreads();
    if (half == 0) {
        float4 o = red4[tt];
        acc.x += o.x; acc.y += o.y; acc.z += o.z; acc.w += o.w;
        *(float4*)(partial + (size_t)(c * 16 + b) * 1024 + h) = acc;
    }
}

__global__ void k_context_reduce(const float* __restrict__ partial,
                                 float* __restrict__ out) {
    int o = blockIdx.x * blockDim.x + threadIdx.x;  // 16384
    int b = o >> 10, h = o & 1023;
    float s = 0.f;
    #pragma unroll
    for (int cc = 0; cc < 16; ++cc) s += partial[(size_t)(cc * 16 + b) * 1024 + h];
    out[o] = s;
}

extern "C" void kernel_launch(void* const* d_in, const int* in_sizes, int n_in,
                              void* d_out, int out_size, void* d_ws, size_t ws_size,
                              hipStream_t stream) {
    const float* hidden = (const float*)d_in[0];
    const float* hseq   = (const float*)d_in[1];
    const int*   masks  = (const int*)d_in[2];
    const float* W      = (const float*)d_in[3];
    const float* b_att  = (const float*)d_in[4];
    const float* v      = (const float*)d_in[5];
    float* out = (float*)d_out;

    // ws layout (float units):
    //   hp[16384] | score_part[131072] | partial[262144] | Wh[524288] | Wl[524288]
    float* wsf        = (float*)d_ws;
    float* hp         = wsf;
    float* score_part = wsf + 16384;
    float* partial    = score_part + 4 * M_SZ;
    unsigned short* Wh = (unsigned short*)(partial + 262144);
    unsigned short* Wl = Wh + 1024 * 1024;
    const size_t WS_FAST_BYTES = (16384 + 131072 + 262144 + 2 * 524288) * sizeof(float);

    hipLaunchKernelGGL(k_hidden_part2, dim3(256), dim3(256), 0, stream, hidden, W, b_att, hp);
    if (ws_size >= WS_FAST_BYTES) {
        hipLaunchKernelGGL(k_split_w,    dim3(1024), dim3(256), 0, stream, W, Wh, Wl);
        hipLaunchKernelGGL(k_score_fast, dim3(1024), dim3(512), 0, stream, hseq, Wh, Wl, hp, v, score_part);
    } else {
        hipLaunchKernelGGL(k_score_mfma, dim3(1024), dim3(512), 0, stream, hseq, W, hp, v, score_part);
    }
    hipLaunchKernelGGL(k_context_sm,     dim3(256), dim3(512), 0, stream, score_part, masks, hseq, partial);
    hipLaunchKernelGGL(k_context_reduce, dim3(64),  dim3(256), 0, stream, partial, out);
}

// Round 6
// 371.671 us; speedup vs baseline: 9.5650x; 1.3462x over previous
//
#include <hip/hip_runtime.h>
#include <math.h>

// Problem constants (S=2048, B=16, H=1024)
#define S_LEN 2048
#define B_SZ  16
#define H_SZ  1024
#define M_SZ  32768

typedef __attribute__((ext_vector_type(8))) _Float16 half8;  // 4 VGPR
typedef __attribute__((ext_vector_type(4))) float f32x4;     // MFMA C/D

__device__ __forceinline__ unsigned pack2h(float a, float b) {
    _Float16 ha = (_Float16)a, hb = (_Float16)b;
    unsigned short ua = __builtin_bit_cast(unsigned short, ha);
    unsigned short ub = __builtin_bit_cast(unsigned short, hb);
    return (unsigned)ua | ((unsigned)ub << 16);
}

// ---------------------------------------------------------------------------
// K1: fused prep.
//  (a) convert W2 = W[:,1024:2048] -> fp16 Wh[1024][1024]
//  (b) hp[b][h] = dot(hidden[b], W1[h]) + b_att[h]  (fp32, proven R5 kernel)
// grid 256 x 256 thr; block handles 4 h-rows for both jobs.
// ---------------------------------------------------------------------------
__global__ __launch_bounds__(256)
void k_prep(const float* __restrict__ hidden,
            const float* __restrict__ W,
            const float* __restrict__ b_att,
            float* __restrict__ hp,
            unsigned short* __restrict__ Wh) {
    __shared__ float hid[B_SZ * H_SZ];                 // 64 KB
    const int t = threadIdx.x;
    #pragma unroll
    for (int i = 0; i < 16; ++i)
        *(float4*)&hid[(t + i * 256) * 4] = *(const float4*)(hidden + (t + i * 256) * 4);

    // (a) W2 -> fp16: row r = bid*4 + (t>>6); 64 threads/row, 16 cols each
    {
        const int r  = blockIdx.x * 4 + (t >> 6);
        const int c0 = (t & 63) * 16;
        const float* src = W + (size_t)r * 2048 + 1024 + c0;
        unsigned short* dst = Wh + (size_t)r * 1024 + c0;
        #pragma unroll
        for (int q = 0; q < 4; ++q) {
            float4 f = *(const float4*)(src + q * 4);
            uint2 u;
            u.x = pack2h(f.x, f.y);
            u.y = pack2h(f.z, f.w);
            *(uint2*)(dst + q * 4) = u;
        }
    }
    __syncthreads();

    // (b) hp: one wave per h, all 16 b
    const int lane = t & 63;
    const int h = blockIdx.x * 4 + (t >> 6);
    const float* w = W + (size_t)h * 2048;
    float acc[16];
    #pragma unroll
    for (int b = 0; b < 16; ++b) acc[b] = 0.f;
    for (int k = 0; k < H_SZ; k += 64) {
        float wv = w[k + lane];
        #pragma unroll
        for (int b = 0; b < 16; ++b) acc[b] = fmaf(wv, hid[b * H_SZ + k + lane], acc[b]);
    }
    #pragma unroll
    for (int b = 0; b < 16; ++b) {
        float s = acc[b];
        s += __shfl_xor(s, 1);  s += __shfl_xor(s, 2);  s += __shfl_xor(s, 4);
        s += __shfl_xor(s, 8);  s += __shfl_xor(s, 16); s += __shfl_xor(s, 32);
        if (lane == 0) hp[b * H_SZ + h] = s + b_att[h];
    }
}

// ===========================================================================
// K2: single-product fp16 MFMA GEMM + tanh + v-dot.
//   score_part[nt][m] = sum_{c in n-tile} v[c]*tanh(X[m]·W2h[c] + hp[m&15][c])
// Tile 128x128, BK=32, 256 thr = 4 waves (2x2), per-wave 64x64.
// LDS rows 64 B (32 fp16), slot16B swizzle: phys = slot ^ ((row>>2)&3),
// applied write+read (reg-staged). 16 KB/buf, 32 KB double-buffered
// -> 3 blocks/CU at launch_bounds(256,3): barriers overlap across blocks.
// ===========================================================================
#define SA    0
#define SB    8192
#define SBUF  16384

__global__ __launch_bounds__(256, 3)
void k_score_f16(const float* __restrict__ X,            // [32768][1024] f32
                 const unsigned short* __restrict__ Wh,  // [1024][1024] fp16
                 const float* __restrict__ hp,           // [16][1024]
                 const float* __restrict__ v,            // [1024]
                 float* __restrict__ score_part) {       // [8][32768]
    __shared__ char lds[2 * SBUF];

    const int t = threadIdx.x;
    // XCD-chunked bijective swizzle (2048 wgs, %8==0), m-panel-major per XCD
    int wg = (blockIdx.x & 7) * 256 + (blockIdx.x >> 3);
    const int m0 = (wg >> 3) * 128;
    const int nt = wg & 7;
    const int n0 = nt * 128;

    const int lane = t & 63, wid = t >> 6;
    const int wm = wid >> 1, wn = wid & 1;       // 2 x 2 waves
    const int lr = lane & 15, lq = lane >> 4;
    const int swr = (lq ^ ((lr >> 2) & 3)) * 16; // read-side slot swizzle

    // staging: row = t>>1 (0..127), shalf = t&1 (k 0..15 / 16..31)
    const int srow = t >> 1, shalf = t & 1;
    const float* Xp = X + (size_t)(m0 + srow) * 1024 + shalf * 16;
    const unsigned short* Wp = Wh + (size_t)(n0 + srow) * 1024 + shalf * 16;
    const int sx = (srow >> 2) & 3;
    const int rowb = srow * 64;
    const int ws0 = rowb + ((shalf * 2 + 0) ^ sx) * 16;
    const int ws1 = rowb + ((shalf * 2 + 1) ^ sx) * 16;

    f32x4 acc[4][4];
    #pragma unroll
    for (int i = 0; i < 4; ++i)
        #pragma unroll
        for (int j = 0; j < 4; ++j) acc[i][j] = (f32x4)0.f;

    float4 ax[4];
    uint4 bx[2];

#define LOADG(kt)                                                              \
    {                                                                          \
        const int ko = (kt) * 32;                                              \
        ax[0] = *(const float4*)(Xp + ko);                                     \
        ax[1] = *(const float4*)(Xp + ko + 4);                                 \
        ax[2] = *(const float4*)(Xp + ko + 8);                                 \
        ax[3] = *(const float4*)(Xp + ko + 12);                                \
        bx[0] = *(const uint4*)(Wp + ko);                                      \
        bx[1] = *(const uint4*)(Wp + ko + 8);                                  \
    }

#define STAGE(buf)                                                             \
    {                                                                          \
        uint4 pa0, pa1;                                                        \
        pa0.x = pack2h(ax[0].x, ax[0].y); pa0.y = pack2h(ax[0].z, ax[0].w);    \
        pa0.z = pack2h(ax[1].x, ax[1].y); pa0.w = pack2h(ax[1].z, ax[1].w);    \
        pa1.x = pack2h(ax[2].x, ax[2].y); pa1.y = pack2h(ax[2].z, ax[2].w);    \
        pa1.z = pack2h(ax[3].x, ax[3].y); pa1.w = pack2h(ax[3].z, ax[3].w);    \
        *(uint4*)((buf) + SA + ws0) = pa0;                                     \
        *(uint4*)((buf) + SA + ws1) = pa1;                                     \
        *(uint4*)((buf) + SB + ws0) = bx[0];                                   \
        *(uint4*)((buf) + SB + ws1) = bx[1];                                   \
    }

    LOADG(0);
    STAGE(lds);
    __syncthreads();

    for (int kt = 0; kt < 32; ++kt) {
        char* cur = lds + (kt & 1) * SBUF;
        char* nxt = lds + ((kt & 1) ^ 1) * SBUF;
        if (kt < 31) LOADG(kt + 1);

        half8 ah[4], bh[4];
        #pragma unroll
        for (int i = 0; i < 4; ++i)
            ah[i] = *(const half8*)(cur + SA + (wm * 64 + i * 16 + lr) * 64 + swr);
        #pragma unroll
        for (int j = 0; j < 4; ++j)
            bh[j] = *(const half8*)(cur + SB + (wn * 64 + j * 16 + lr) * 64 + swr);

        #pragma unroll
        for (int i = 0; i < 4; ++i)
            #pragma unroll
            for (int j = 0; j < 4; ++j)
                acc[i][j] = __builtin_amdgcn_mfma_f32_16x16x32_f16(ah[i], bh[j], acc[i][j], 0, 0, 0);

        if (kt < 31) STAGE(nxt);
        __syncthreads();
    }

    // epilogue: D[row = wm*64+i*16+lq*4+r][col = wn*64+j*16+lr]
    float* red = (float*)lds;          // [2][128] floats; buffer 0 is dead
    #pragma unroll
    for (int i = 0; i < 4; ++i) {
        #pragma unroll
        for (int r = 0; r < 4; ++r) {
            const int b = lq * 4 + r;  // global row & 15
            float s = 0.f;
            #pragma unroll
            for (int j = 0; j < 4; ++j) {
                const int c = n0 + wn * 64 + j * 16 + lr;
                s += v[c] * tanhf(acc[i][j][r] + hp[b * H_SZ + c]);
            }
            s += __shfl_xor(s, 1);
            s += __shfl_xor(s, 2);
            s += __shfl_xor(s, 4);
            s += __shfl_xor(s, 8);
            if (lr == 0)
                red[wn * 128 + wm * 64 + i * 16 + lq * 4 + r] = s;
        }
    }
    __syncthreads();
    if (t < 128)
        score_part[nt * M_SZ + m0 + t] = red[t] + red[128 + t];
#undef LOADG
#undef STAGE
}

// ---------------------------------------------------------------------------
// K3: fused softmax + context partial. Block (c,b): 64 s-steps for batch b.
// Phase 1: threads 0..63 fold 8 score partials, mask, softmax -> w[s,b].
// Phase 2: 256 threads x float4 accumulate 64 s-steps over 1024 h.
// ---------------------------------------------------------------------------
__global__ __launch_bounds__(256)
void k_context_sm(const float* __restrict__ part,    // [8][32768]
                  const int* __restrict__ masks,
                  const float* __restrict__ X,
                  float* __restrict__ partial) {     // [32][16][1024]
    __shared__ float wlds[64];

    const int t = threadIdx.x;
    const int b = blockIdx.x & 15;
    const int c = blockIdx.x >> 4;

    if (t < 64) {
        const int s = c * 64 + t;
        float vals[16];
        float mx = -INFINITY;
        #pragma unroll
        for (int bb = 0; bb < 16; ++bb) {
            const int m = s * 16 + bb;
            float sc = 0.f;
            #pragma unroll
            for (int p = 0; p < 8; ++p) sc += part[p * M_SZ + m];
            sc = masks[m] ? sc : -1e10f;
            vals[bb] = sc;
            mx = fmaxf(mx, sc);
        }
        float sum = 0.f;
        #pragma unroll
        for (int bb = 0; bb < 16; ++bb) { vals[bb] = __expf(vals[bb] - mx); sum += vals[bb]; }
        wlds[t] = vals[b] / sum;
    }
    __syncthreads();

    const int h = t * 4;
    float4 acc = make_float4(0.f, 0.f, 0.f, 0.f);
    #pragma unroll 4
    for (int i = 0; i < 64; ++i) {
        float w = wlds[i];
        float4 x = *(const float4*)(X + ((size_t)((c * 64 + i) * 16 + b)) * 1024 + h);
        acc.x += w * x.x; acc.y += w * x.y; acc.z += w * x.z; acc.w += w * x.w;
    }
    *(float4*)(partial + (size_t)(c * 16 + b) * 1024 + h) = acc;
}

__global__ void k_context_reduce(const float* __restrict__ partial,
                                 float* __restrict__ out) {
    int o = blockIdx.x * blockDim.x + threadIdx.x;  // 16384
    int b = o >> 10, h = o & 1023;
    float s = 0.f;
    #pragma unroll
    for (int cc = 0; cc < 32; ++cc) s += partial[(size_t)(cc * 16 + b) * 1024 + h];
    out[o] = s;
}

extern "C" void kernel_launch(void* const* d_in, const int* in_sizes, int n_in,
                              void* d_out, int out_size, void* d_ws, size_t ws_size,
                              hipStream_t stream) {
    const float* hidden = (const float*)d_in[0];
    const float* hseq   = (const float*)d_in[1];
    const int*   masks  = (const int*)d_in[2];
    const float* W      = (const float*)d_in[3];
    const float* b_att  = (const float*)d_in[4];
    const float* v      = (const float*)d_in[5];
    float* out = (float*)d_out;

    // ws layout (float units), total 1,327,104 f = 5.31 MB (< R5-proven 5.84):
    //   hp[16384] | score_part[8*32768] | partial[32*16*1024] | Wh (fp16, 512K f-units)
    float* wsf        = (float*)d_ws;
    float* hp         = wsf;
    float* score_part = wsf + 16384;
    float* partial    = score_part + 8 * M_SZ;
    unsigned short* Wh = (unsigned short*)(partial + 32 * 16 * 1024);

    hipLaunchKernelGGL(k_prep,           dim3(256),  dim3(256), 0, stream, hidden, W, b_att, hp, Wh);
    hipLaunchKernelGGL(k_score_f16,      dim3(2048), dim3(256), 0, stream, hseq, Wh, hp, v, score_part);
    hipLaunchKernelGGL(k_context_sm,     dim3(512),  dim3(256), 0, stream, score_part, masks, hseq, partial);
    hipLaunchKernelGGL(k_context_reduce, dim3(64),   dim3(256), 0, stream, partial, out);
}